// Round 17
// baseline (654.707 us; speedup 1.0000x reference)
//
#include <hip/hip_runtime.h>
#include <cstdint>

#define DEV __device__ __forceinline__

typedef __attribute__((ext_vector_type(4))) float f32x4;
typedef __attribute__((ext_vector_type(4))) float float4v;
typedef __attribute__((ext_vector_type(8))) short bf16x8;
typedef __attribute__((ext_vector_type(4))) unsigned short ushort4v;
typedef __attribute__((ext_vector_type(2))) unsigned int uint2v;
typedef unsigned short u16;

static constexpr int Bb = 4, Tt = 2048, Hh = 16, KVh = 4, Dd = 128;
static constexpr int NQKV = 3072;   // fused projection width: 2048 q + 512 k + 512 v

DEV u16 f2bf(float x) {
    union { float f; unsigned u; } v; v.f = x;
    unsigned r = v.u + 0x7FFF + ((v.u >> 16) & 1);
    return (u16)(r >> 16);
}
DEV float bf2f(u16 b) {
    union { unsigned u; float f; } v; v.u = ((unsigned)b) << 16;
    return v.f;
}
DEV unsigned cvtpk(float lo, float hi) {
    unsigned d;
    asm("v_cvt_pk_bf16_f32 %0, %1, %2" : "=v"(d) : "v"(lo), "v"(hi));
    return d;
}

typedef const void __attribute__((address_space(1)))* gas1;
typedef void __attribute__((address_space(3)))* las3;
DEV void gload16(const void* g, void* l) {
    __builtin_amdgcn_global_load_lds((gas1)g, (las3)l, 16, 0, 0);
}

// ---------------- cast x -> bf16 ----------------
__global__ __launch_bounds__(256) void cast_k(const float* __restrict__ x, u16* __restrict__ xb, long n4) {
    long id = (long)blockIdx.x * 256 + threadIdx.x;
    if (id >= n4) return;
    float4v v = *(const float4v*)&x[id * 4];
    ushort4v o;
    o[0] = f2bf(v[0]); o[1] = f2bf(v[1]); o[2] = f2bf(v[2]); o[3] = f2bf(v[3]);
    *(ushort4v*)&xb[id * 4] = o;
}

// ---------------- transpose+cast weight: W (K x N) f32 -> Wt (N x K) bf16 ----------------
__global__ __launch_bounds__(256) void twt_k(const float* __restrict__ W, u16* __restrict__ Wt, int K, int N) {
    __shared__ float tile[32][33];
    int tx = threadIdx.x, ty = threadIdx.y;
    long n0 = (long)blockIdx.x * 32, k0 = (long)blockIdx.y * 32;
#pragma unroll
    for (int j = 0; j < 4; j++)
        tile[ty + j * 8][tx] = W[(k0 + ty + j * 8) * (long)N + n0 + tx];
    __syncthreads();
#pragma unroll
    for (int j = 0; j < 4; j++)
        Wt[(n0 + ty + j * 8) * (long)K + k0 + tx] = f2bf(tile[tx][ty + j * 8]);
}

// ---------------- transpose v (from fused qkv, stride 3072, col 2560) -> vt (b,kv,d,t) ----------------
__global__ __launch_bounds__(256) void tv_k(const u16* __restrict__ qkv, u16* __restrict__ vt) {
    __shared__ u16 tile[32][33];
    int tx = threadIdx.x, ty = threadIdx.y;
    int d0 = blockIdx.x * 32;
    int t0 = blockIdx.y * 32;
    int bk = blockIdx.z;
    int b = bk >> 2, kv = bk & 3;
#pragma unroll
    for (int j = 0; j < 4; j++)
        tile[ty + j * 8][tx] = qkv[(long)(b * Tt + t0 + ty + j * 8) * NQKV + 2560 + kv * Dd + d0 + tx];
    __syncthreads();
#pragma unroll
    for (int j = 0; j < 4; j++)
        vt[((long)(b * KVh + kv) * Dd + d0 + ty + j * 8) * Tt + t0 + tx] = tile[tx][ty + j * 8];
}

// ---------------- rope tables: [t][i], i<64 ----------------
__global__ __launch_bounds__(256) void tables_k(float* __restrict__ cosb, float* __restrict__ sinb) {
    int id = blockIdx.x * 256 + threadIdx.x; // < 2048*64
    int t = id >> 6, i = id & 63;
    float inv = powf(10000.0f, -(float)i * (1.0f / 64.0f));
    float f = (float)t * inv;
    cosb[id] = cosf(f);
    sinb[id] = sinf(f);
}

// ---------------- rope v2: vectorized (8 lanes of rotation pair per thread) ----------------
__global__ __launch_bounds__(256) void rope_k(u16* __restrict__ p, const float* __restrict__ cosb,
                                              const float* __restrict__ sinb, int nh, float scale, int total8,
                                              long rowstride, int colbase) {
    int id = blockIdx.x * 256 + threadIdx.x;
    if (id >= total8) return;
    int i8 = id & 7;
    int bth = id >> 3;
    int row = bth / nh;
    int t = row % Tt;
    u16* ptr = p + (long)row * rowstride + colbase + (bth % nh) * Dd + i8 * 8;
    ushort4v a0 = *(ushort4v*)&ptr[0];
    ushort4v a1 = *(ushort4v*)&ptr[4];
    ushort4v b0 = *(ushort4v*)&ptr[64];
    ushort4v b1 = *(ushort4v*)&ptr[68];
    const float4v c0 = *(const float4v*)&cosb[t * 64 + i8 * 8];
    const float4v c1 = *(const float4v*)&cosb[t * 64 + i8 * 8 + 4];
    const float4v s0 = *(const float4v*)&sinb[t * 64 + i8 * 8];
    const float4v s1 = *(const float4v*)&sinb[t * 64 + i8 * 8 + 4];
    ushort4v oa0, oa1, ob0, ob1;
#pragma unroll
    for (int j = 0; j < 4; j++) {
        float x1 = bf2f(a0[j]), x2 = bf2f(b0[j]);
        oa0[j] = f2bf((x1 * c0[j] - x2 * s0[j]) * scale);
        ob0[j] = f2bf((x2 * c0[j] + x1 * s0[j]) * scale);
        float y1 = bf2f(a1[j]), y2 = bf2f(b1[j]);
        oa1[j] = f2bf((y1 * c1[j] - y2 * s1[j]) * scale);
        ob1[j] = f2bf((y2 * c1[j] + y1 * s1[j]) * scale);
    }
    *(ushort4v*)&ptr[0] = oa0;
    *(ushort4v*)&ptr[4] = oa1;
    *(ushort4v*)&ptr[64] = ob0;
    *(ushort4v*)&ptr[68] = ob1;
}

// ---------------- GEMM v4: 256x128, 8 waves, BK=64, 3-slot ring, swizzled LDS, 2-phase interleave ----------------
template <int F32OUT>
__global__ __launch_bounds__(512) void gemm_k(const u16* __restrict__ A, const u16* __restrict__ Bt,
                                              void* __restrict__ Cout, int M, int N, int K) {
    __shared__ u16 lds[3][24576];   // per slot: A 256x64 (16384 u16) | B 128x64 (8192 u16)
    const int tid = threadIdx.x;
    const int lane = tid & 63;
    const int w = __builtin_amdgcn_readfirstlane(tid >> 6);   // 0..7
    const int wm = w >> 1, wn = w & 1;
    const long m0 = (long)blockIdx.x * 256;
    const long n0 = (long)blockIdx.y * 128;
    const int NT = K >> 6;
    const int l8 = lane >> 3, s8 = lane & 7;
    const int fr = lane & 15, kg = lane >> 4;   // kg 0..3

    auto stageA = [&](int t) {
        u16* base = lds[t % 3];
        const long ko = (long)t * 64;
#pragma unroll
        for (int c4 = 0; c4 < 4; c4++) {       // A: 4 chunks of 1KB (8 rows each)
            int c = w * 4 + c4;
            int row = c * 8 + l8;
            int slog = s8 ^ (l8 & 7);
            gload16(A + (m0 + row) * (long)K + ko + slog * 8, base + c * 512);
        }
    };
    auto stageB = [&](int t) {
        u16* base = lds[t % 3];
        const long ko = (long)t * 64;
#pragma unroll
        for (int c2 = 0; c2 < 2; c2++) {       // B: 2 chunks
            int c = w * 2 + c2;
            int row = c * 8 + l8;
            int slog = s8 ^ (l8 & 7);
            gload16(Bt + (n0 + row) * (long)K + ko + slog * 8, base + 16384 + c * 512);
        }
    };

    f32x4 acc[4][4] = {};
    stageA(0); stageB(0);
    if (NT > 1) {
        stageA(1); stageB(1);
        asm volatile("s_waitcnt vmcnt(6)" ::: "memory");
    } else {
        asm volatile("s_waitcnt vmcnt(0)" ::: "memory");
    }
    __builtin_amdgcn_s_barrier();

    for (int t = 0; t < NT; ++t) {
        const u16* sa = lds[t % 3];
        const u16* sb = sa + 16384;
        // ---- phase 0 (ks = 0) ----
        {
            bf16x8 af[4], bfr[4];
#pragma unroll
            for (int i = 0; i < 4; i++) {
                const int row = wm * 64 + i * 16 + fr;
                af[i] = *(const bf16x8*)&sa[row * 64 + ((kg ^ (row & 7)) * 8)];
                const int col = wn * 64 + i * 16 + fr;
                bfr[i] = *(const bf16x8*)&sb[col * 64 + ((kg ^ (col & 7)) * 8)];
            }
            if (t + 2 < NT) stageA(t + 2);
            __builtin_amdgcn_s_barrier();
            __builtin_amdgcn_s_setprio(1);
#pragma unroll
            for (int i = 0; i < 4; i++)
#pragma unroll
                for (int j = 0; j < 4; j++)
                    acc[i][j] = __builtin_amdgcn_mfma_f32_16x16x32_bf16(af[i], bfr[j], acc[i][j], 0, 0, 0);
            __builtin_amdgcn_s_setprio(0);
            __builtin_amdgcn_s_barrier();
        }
        // ---- phase 1 (ks = 1) ----
        {
            bf16x8 af[4], bfr[4];
#pragma unroll
            for (int i = 0; i < 4; i++) {
                const int row = wm * 64 + i * 16 + fr;
                af[i] = *(const bf16x8*)&sa[row * 64 + (((4 + kg) ^ (row & 7)) * 8)];
                const int col = wn * 64 + i * 16 + fr;
                bfr[i] = *(const bf16x8*)&sb[col * 64 + (((4 + kg) ^ (col & 7)) * 8)];
            }
            if (t + 2 < NT) stageB(t + 2);
            if (t + 2 < NT)
                asm volatile("s_waitcnt vmcnt(6)" ::: "memory");
            else if (t + 1 < NT)
                asm volatile("s_waitcnt vmcnt(0)" ::: "memory");
            __builtin_amdgcn_s_barrier();
            __builtin_amdgcn_s_setprio(1);
#pragma unroll
            for (int i = 0; i < 4; i++)
#pragma unroll
                for (int j = 0; j < 4; j++)
                    acc[i][j] = __builtin_amdgcn_mfma_f32_16x16x32_bf16(af[i], bfr[j], acc[i][j], 0, 0, 0);
            __builtin_amdgcn_s_setprio(0);
            __builtin_amdgcn_s_barrier();
        }
    }

    const int orow = (lane >> 4) * 4, ocol = lane & 15;
#pragma unroll
    for (int i = 0; i < 4; i++)
#pragma unroll
        for (int j = 0; j < 4; j++) {
            long r = m0 + wm * 64 + i * 16 + orow;
            long c = n0 + wn * 64 + j * 16 + ocol;
#pragma unroll
            for (int t = 0; t < 4; t++) {
                if (F32OUT)
                    ((float*)Cout)[(r + t) * N + c] = acc[i][j][t];
                else
                    ((u16*)Cout)[(r + t) * N + c] = f2bf(acc[i][j][t]);
            }
        }
}

// ---------------- flash attention v14: V direct from L2, pair-balanced 4 blocks/CU, QK-ahead ----------------
// LDS pipe was the most-loaded resource (18 b128/wave-tile). V fragments are now read DIRECTLY
// from global (vt panel is L2-resident via XCD grouping; v5's verified address pattern, fully
// coalesced 16x128B per fragment) -> LDS traffic -45%, no stage_v, LDS 33KB -> 4 blocks/CU.
// Pair-balanced pass loop restored (v8, verified): block (x=kvb, y=bid) does qt {63-bid, bid},
// exactly 65 tiles/block, 512 blocks ALL co-resident (4/CU capacity) -> zero tail.
// K in 3-slot ring + QK-ahead (v13, verified); per-tile math verbatim.
__global__ __launch_bounds__(256, 4) void attn_k(const u16* __restrict__ qkv,
                                                 const u16* __restrict__ vt, u16* __restrict__ o) {
    __shared__ u16 kl[3][4096];
    __shared__ u16 pT[4][2][16][36];
    const int tid = threadIdx.x;
    const int lane = tid & 63;
    const int w = tid >> 6;
    const int kvb = blockIdx.x;       // kv + 4*b  (XCD group key)
    const int kv = kvb & 3, b = kvb >> 2;
    const int bid = blockIdx.y;       // 0..31 pair index
    const int h = kv * 4 + w;
    const int fr = lane & 15, kg = lane >> 4;
    const long HD = (long)Hh * Dd;               // output row stride (2048)
    const long QS = (long)NQKV;                  // fused row stride (3072)
    const long kbase = (long)b * Tt * QS + 2048 + (long)kv * Dd;
    const long vbase = ((long)(b * KVh + kv)) * (long)Dd * Tt;

    auto stage_k = [&](int t) {
        const int s0 = t * 32;
        const int lh = lane >> 4;     // 0..3
#pragma unroll
        for (int j = 0; j < 2; j++) { // K: 8 chunks of 1KB, chunk c = j*4+w
            int c = j * 4 + w;
            int row = c * 4 + lh;
            int c16 = (lane & 15) ^ (row & 7);
            gload16(qkv + kbase + (long)(s0 + row) * QS + c16 * 8, &kl[t % 3][c * 512]);
        }
    };

    for (int pass = 0; pass < 2; ++pass) {
        const int qt = pass ? bid : 63 - bid;
        const int q0 = qt * 32;
        const long qbase = (long)(b * Tt + q0) * QS + (long)h * Dd;
        const long obase = (long)(b * Tt + q0) * HD + (long)h * Dd;
        const int nt = qt + 1;

        bf16x8 qa[2][4];
#pragma unroll
        for (int qi = 0; qi < 2; qi++)
#pragma unroll
            for (int kc = 0; kc < 4; kc++)
                qa[qi][kc] = *(const bf16x8*)&qkv[qbase + (long)(qi * 16 + fr) * QS + kc * 32 + kg * 8];

        // QK^T of one 32-k tile from a given kl slot into st[kf][qi]
        auto qkcomp = [&](const u16* klbuf, f32x4 (&st)[2][2]) {
            __builtin_amdgcn_s_setprio(1);
#pragma unroll
            for (int kf = 0; kf < 2; kf++) {
                const int rr = kf * 16 + fr;
                bf16x8 ka[4];
#pragma unroll
                for (int kc = 0; kc < 4; kc++)
                    ka[kc] = *(const bf16x8*)&klbuf[rr * 128 + (((kc * 4 + kg) ^ (rr & 7)) * 8)];
#pragma unroll
                for (int kc = 0; kc < 4; kc++) {
                    st[kf][0] = __builtin_amdgcn_mfma_f32_16x16x32_bf16(ka[kc], qa[0][kc], st[kf][0], 0, 0, 0);
                    st[kf][1] = __builtin_amdgcn_mfma_f32_16x16x32_bf16(ka[kc], qa[1][kc], st[kf][1], 0, 0, 0);
                }
            }
            __builtin_amdgcn_s_setprio(0);
        };

        f32x4 ot[8][2] = {};          // O^T accumulator: [df][qi]
        float mr0 = -1e30f, mr1 = -1e30f, lr0 = 0.0f, lr1 = 0.0f;

        stage_k(0);
        if (nt > 1) stage_k(1);
        __syncthreads();

        f32x4 stA[2][2] = {};
        qkcomp(kl[0], stA);

        for (int it = 0; it < nt; ++it) {
            if (it + 2 < nt) stage_k(it + 2);
            const int s0 = it * 32;
            // ---- causal mask (diagonal tile only) ----
            if (it == nt - 1) {
#pragma unroll
                for (int kf = 0; kf < 2; kf++)
#pragma unroll
                    for (int qi = 0; qi < 2; qi++) {
                        const int qq = q0 + qi * 16 + fr;
                        const int kb0 = s0 + kf * 16 + kg * 4;
#pragma unroll
                        for (int r = 0; r < 4; r++)
                            if (kb0 + r > qq) stA[kf][qi][r] = -1e30f;
                    }
            }
            // ---- in-register online softmax (base-2 domain) ----
            float tm0 = stA[0][0][0], tm1 = stA[0][1][0];
#pragma unroll
            for (int kf = 0; kf < 2; kf++)
#pragma unroll
                for (int r = 0; r < 4; r++)
                    if (kf | r) {
                        tm0 = fmaxf(tm0, stA[kf][0][r]);
                        tm1 = fmaxf(tm1, stA[kf][1][r]);
                    }
            tm0 = fmaxf(tm0, __shfl_xor(tm0, 16)); tm0 = fmaxf(tm0, __shfl_xor(tm0, 32));
            tm1 = fmaxf(tm1, __shfl_xor(tm1, 16)); tm1 = fmaxf(tm1, __shfl_xor(tm1, 32));
            if (__any(fmaxf(tm0 - mr0, tm1 - mr1) > 8.0f)) {
                float mn0 = fmaxf(mr0, tm0), mn1 = fmaxf(mr1, tm1);
                float al0 = __builtin_amdgcn_exp2f(mr0 - mn0);
                float al1 = __builtin_amdgcn_exp2f(mr1 - mn1);
                mr0 = mn0; mr1 = mn1;
                lr0 *= al0; lr1 *= al1;
#pragma unroll
                for (int df = 0; df < 8; df++) { ot[df][0] *= al0; ot[df][1] *= al1; }
            }
            float rs0 = 0.0f, rs1 = 0.0f;
#pragma unroll
            for (int kf = 0; kf < 2; kf++)
#pragma unroll
                for (int r = 0; r < 4; r++) {
                    stA[kf][0][r] = __builtin_amdgcn_exp2f(stA[kf][0][r] - mr0); rs0 += stA[kf][0][r];
                    stA[kf][1][r] = __builtin_amdgcn_exp2f(stA[kf][1][r] - mr1); rs1 += stA[kf][1][r];
                }
            rs0 += __shfl_xor(rs0, 16); rs0 += __shfl_xor(rs0, 32);
            rs1 += __shfl_xor(rs1, 16); rs1 += __shfl_xor(rs1, 32);
            lr0 += rs0; lr1 += rs1;
            // ---- stage P^T for BOTH qi ----
#pragma unroll
            for (int qi = 0; qi < 2; qi++) {
                uint2v w0;
                w0[0] = cvtpk(stA[0][qi][0], stA[0][qi][1]);
                w0[1] = cvtpk(stA[0][qi][2], stA[0][qi][3]);
                *(uint2v*)&pT[w][qi][fr][kg * 4] = w0;
                uint2v w1;
                w1[0] = cvtpk(stA[1][qi][0], stA[1][qi][1]);
                w1[1] = cvtpk(stA[1][qi][2], stA[1][qi][3]);
                *(uint2v*)&pT[w][qi][fr][16 + kg * 4] = w1;
            }
            // ---- QK-ahead: compute next tile's S^T while softmax results settle ----
            f32x4 stB[2][2] = {};
            if (it + 1 < nt) qkcomp(kl[(it + 1) % 3], stB);
            // ---- PV: V fragments DIRECT from global (L2-hot), each feeds both qi ----
            {
                bf16x8 bq0 = *(const bf16x8*)&pT[w][0][fr][kg * 8];
                bf16x8 bq1 = *(const bf16x8*)&pT[w][1][fr][kg * 8];
                __builtin_amdgcn_s_setprio(1);
#pragma unroll
                for (int df = 0; df < 8; df++) {
                    bf16x8 va = *(const bf16x8*)&vt[vbase + (long)(df * 16 + fr) * Tt + s0 + kg * 8];
                    ot[df][0] = __builtin_amdgcn_mfma_f32_16x16x32_bf16(va, bq0, ot[df][0], 0, 0, 0);
                    ot[df][1] = __builtin_amdgcn_mfma_f32_16x16x32_bf16(va, bq1, ot[df][1], 0, 0, 0);
                }
                __builtin_amdgcn_s_setprio(0);
            }
            __syncthreads();
#pragma unroll
            for (int kf = 0; kf < 2; kf++)
#pragma unroll
                for (int qi = 0; qi < 2; qi++)
                    stA[kf][qi] = stB[kf][qi];
        }
        // ---- store: lane holds 4 consecutive d (row) for q (col) = qi*16+fr ----
        const float il0 = 1.0f / lr0, il1 = 1.0f / lr1;
#pragma unroll
        for (int df = 0; df < 8; df++) {
            uint2v w0, w1;
            w0[0] = cvtpk(ot[df][0][0] * il0, ot[df][0][1] * il0);
            w0[1] = cvtpk(ot[df][0][2] * il0, ot[df][0][3] * il0);
            w1[0] = cvtpk(ot[df][1][0] * il1, ot[df][1][1] * il1);
            w1[1] = cvtpk(ot[df][1][2] * il1, ot[df][1][3] * il1);
            *(uint2v*)&o[obase + (long)(fr) * HD + df * 16 + kg * 4] = w0;
            *(uint2v*)&o[obase + (long)(16 + fr) * HD + df * 16 + kg * 4] = w1;
        }
    }
}

extern "C" void kernel_launch(void* const* d_in, const int* in_sizes, int n_in,
                              void* d_out, int out_size, void* d_ws, size_t ws_size,
                              hipStream_t stream) {
    (void)in_sizes; (void)n_in; (void)out_size; (void)ws_size;
    const float* x = (const float*)d_in[0];
    const float* Wq = (const float*)d_in[1];
    const float* Wk = (const float*)d_in[2];
    const float* Wv = (const float*)d_in[3];
    const float* Wo = (const float*)d_in[4];

    char* ws = (char*)d_ws;
    u16* xb   = (u16*)(ws + 0);            // 33.5MB  (b,t,c) bf16; later reused as attn output (b,t,h,d)
    u16* vtb  = (u16*)(ws + 50331648);     // 8.4MB   (b,kv,d,t)
    u16* wqt  = (u16*)(ws + 58720256);     // 8.4MB   (first part of fused Wt, 3072 x 2048)
    u16* wkt  = (u16*)(ws + 67108864);     // 2.1MB   (contiguous after wqt)
    u16* wvt  = (u16*)(ws + 69206016);     // 2.1MB   (contiguous after wkt)
    u16* wot  = (u16*)(ws + 71303168);     // 8.4MB
    float* cosb = (float*)(ws + 79691776); // 0.5MB
    float* sinb = (float*)(ws + 80216064); // 0.5MB
    u16* qkv = (u16*)d_out;                // fused qkv (8192 x 3072) bf16 lives in d_out until final GEMM

    dim3 tb(32, 8);
    cast_k<<<16384, 256, 0, stream>>>(x, xb, 4194304);
    twt_k<<<dim3(64, 64), tb, 0, stream>>>(Wq, wqt, 2048, 2048);
    twt_k<<<dim3(16, 64), tb, 0, stream>>>(Wk, wkt, 2048, 512);
    twt_k<<<dim3(16, 64), tb, 0, stream>>>(Wv, wvt, 2048, 512);
    twt_k<<<dim3(64, 64), tb, 0, stream>>>(Wo, wot, 2048, 2048);
    tables_k<<<512, 256, 0, stream>>>(cosb, sinb);

    // fused QKV projection: one GEMM, N = 2048+512+512
    gemm_k<0><<<dim3(32, 24), 512, 0, stream>>>(xb, wqt, qkv, 8192, NQKV, 2048);

    // q scale = (1/sqrt(128)) * log2(e) -> softmax runs in exp2 domain
    rope_k<<<4096, 256, 0, stream>>>(qkv, cosb, sinb, 16, 0.1275174316f, 1048576, NQKV, 0);
    rope_k<<<1024, 256, 0, stream>>>(qkv, cosb, sinb, 4, 1.0f, 262144, NQKV, 2048);
    tv_k<<<dim3(4, 64, 16), tb, 0, stream>>>(qkv, vtb);

    attn_k<<<dim3(16, 32), 256, 0, stream>>>(qkv, vtb, xb);

    gemm_k<1><<<dim3(32, 16), 512, 0, stream>>>(xb, wot, d_out, 8192, 2048, 2048);
}